// Round 4
// baseline (748.450 us; speedup 1.0000x reference)
//
#include <hip/hip_runtime.h>

#define NB 32
#define NPTS 1024
#define NP 256
#define NS 16
#define NC 256
#define NH 128
#define NOUT 97
#define GTN 16

// ---------------------------------------------------------------------------
// Prep: w0ft[c][o] = sa_w0[o][3+c]; w0x[d][o] = sa_w0[o][d];
// quad layouts wq[(c4*128+o)*4+k] = W[o][c4*4+k]  -> one dwordx4 per c4-step.
// ---------------------------------------------------------------------------
__global__ __launch_bounds__(256) void prep_kernel(
    const float* __restrict__ sa_w0, const float* __restrict__ sa_w1,
    const float* __restrict__ sa_w2, const float* __restrict__ fc_w1,
    const float* __restrict__ fc_w2, const float* __restrict__ fc_w3,
    float* __restrict__ w0ft, float* __restrict__ w0x,
    float* __restrict__ w1q, float* __restrict__ w2q,
    float* __restrict__ fq1, float* __restrict__ fq2,
    float* __restrict__ w3q)
{
  int t = blockIdx.x * 256 + threadIdx.x;
  if (t < 256 * 128) { int c = t >> 7, o = t & 127; w0ft[t] = sa_w0[o * 259 + 3 + c]; }
  if (t < 3 * 128)   { int d = t >> 7, o = t & 127; w0x[t]  = sa_w0[o * 259 + d]; }
  if (t < 128 * 128) {
    int c = t >> 7, o = t & 127;
    int qi = ((c >> 2) * 128 + o) * 4 + (c & 3);
    w1q[qi] = sa_w1[o * 128 + c];
    w2q[qi] = sa_w2[o * 128 + c];
    fq1[qi] = fc_w1[o * 128 + c];
    fq2[qi] = fc_w2[o * 128 + c];
    w3q[qi] = (o < NOUT) ? fc_w3[o * 128 + c] : 0.0f;
  }
}

// ---------------------------------------------------------------------------
// Fused FPS + gfeat.
//   blocks [0, NB):      FPS, one 64-lane wave per batch. Packed u64-key
//                        argmax: dist>=0 so f32 order == u32 order;
//                        key = (bits<<32)|(1023-idx) -> max == first-max.
//   blocks [NB, NB+2048): G[b][n][o] = sum_c features[b][c][n] * w0ft[c][o]
// ---------------------------------------------------------------------------
__global__ __launch_bounds__(128) void fused_fps_gfeat_kernel(
    const float* __restrict__ xyz, int* __restrict__ inds,
    const float* __restrict__ features, const float* __restrict__ w0ft,
    float* __restrict__ G)
{
  __shared__ __align__(16) float smem[NC * 20];

  if (blockIdx.x < NB) {
    if (threadIdx.x >= 64) return;                // single wave
    const int b = blockIdx.x;
    const int lane = threadIdx.x;
    float* s_x = smem;
    float* s_y = smem + NPTS;
    float* s_z = smem + 2 * NPTS;
    const float* xb = xyz + b * NPTS * 3;

    float pts[48];
    const float4* src = reinterpret_cast<const float4*>(xb + lane * 48);
#pragma unroll
    for (int r = 0; r < 12; ++r) {
      float4 v = src[r];
      pts[4 * r + 0] = v.x; pts[4 * r + 1] = v.y;
      pts[4 * r + 2] = v.z; pts[4 * r + 3] = v.w;
    }
    float dist[16];
#pragma unroll
    for (int j = 0; j < 16; ++j) {
      s_x[lane * 16 + j] = pts[3 * j + 0];
      s_y[lane * 16 + j] = pts[3 * j + 1];
      s_z[lane * 16 + j] = pts[3 * j + 2];
      dist[j] = 1e10f;
    }
    int far = 0;
    for (int i = 0; i < NP; ++i) {
      if (lane == 0) inds[b * NP + i] = far;
      float cx = s_x[far], cy = s_y[far], cz = s_z[far];
      unsigned long long bk = 0ull;
#pragma unroll
      for (int j = 0; j < 16; ++j) {
#pragma clang fp contract(off)
        float dx = pts[3 * j + 0] - cx;
        float dy = pts[3 * j + 1] - cy;
        float dz = pts[3 * j + 2] - cz;
        float d = (dx * dx + dy * dy) + dz * dz;
        float nd = fminf(dist[j], d);
        dist[j] = nd;
        unsigned long long key =
            ((unsigned long long)__float_as_uint(nd) << 32)
            | (unsigned)(1023 - (lane * 16 + j));
        bk = (key > bk) ? key : bk;     // equal dist -> smaller idx has larger key
      }
#pragma unroll
      for (int off = 1; off < 64; off <<= 1) {
        unsigned long long ok = __shfl_xor(bk, off);
        bk = (ok > bk) ? ok : bk;
      }
      far = 1023 - (int)(unsigned)bk;
    }
    return;
  }

  const int blk = blockIdx.x - NB;
  const int b  = blk >> 6;
  const int n0 = (blk & 63) * GTN;
  const int o  = threadIdx.x;
  float* ft = smem;
  const float* fb = features + b * NC * NPTS;
#pragma unroll
  for (int r = 0; r < 2; ++r) {
    int c = r * 128 + o;
    const float4* srcf = reinterpret_cast<const float4*>(fb + c * NPTS + n0);
    float4 v0 = srcf[0], v1 = srcf[1], v2 = srcf[2], v3 = srcf[3];
    *reinterpret_cast<float4*>(&ft[c * 20 + 0])  = v0;
    *reinterpret_cast<float4*>(&ft[c * 20 + 4])  = v1;
    *reinterpret_cast<float4*>(&ft[c * 20 + 8])  = v2;
    *reinterpret_cast<float4*>(&ft[c * 20 + 12]) = v3;
  }
  __syncthreads();
  float acc[GTN];
#pragma unroll
  for (int j = 0; j < GTN; ++j) acc[j] = 0.0f;
  for (int c = 0; c < NC; ++c) {
    float w = w0ft[c * 128 + o];
    float4 v0 = *reinterpret_cast<const float4*>(&ft[c * 20 + 0]);
    float4 v1 = *reinterpret_cast<const float4*>(&ft[c * 20 + 4]);
    float4 v2 = *reinterpret_cast<const float4*>(&ft[c * 20 + 8]);
    float4 v3 = *reinterpret_cast<const float4*>(&ft[c * 20 + 12]);
    acc[0]  = fmaf(w, v0.x, acc[0]);  acc[1]  = fmaf(w, v0.y, acc[1]);
    acc[2]  = fmaf(w, v0.z, acc[2]);  acc[3]  = fmaf(w, v0.w, acc[3]);
    acc[4]  = fmaf(w, v1.x, acc[4]);  acc[5]  = fmaf(w, v1.y, acc[5]);
    acc[6]  = fmaf(w, v1.z, acc[6]);  acc[7]  = fmaf(w, v1.w, acc[7]);
    acc[8]  = fmaf(w, v2.x, acc[8]);  acc[9]  = fmaf(w, v2.y, acc[9]);
    acc[10] = fmaf(w, v2.z, acc[10]); acc[11] = fmaf(w, v2.w, acc[11]);
    acc[12] = fmaf(w, v3.x, acc[12]); acc[13] = fmaf(w, v3.y, acc[13]);
    acc[14] = fmaf(w, v3.z, acc[14]); acc[15] = fmaf(w, v3.w, acc[15]);
  }
#pragma unroll
  for (int j = 0; j < GTN; ++j)
    G[(b * NPTS + n0 + j) * NH + o] = acc[j];
}

// 16 chained FMAs: acc[0..15] += WK * x[(XP)+0..15], XP uniform -> s_load
#define FMA16(WK, XP) \
  { const float4 a0 = *reinterpret_cast<const float4*>((XP) + 0);  \
    const float4 a1 = *reinterpret_cast<const float4*>((XP) + 4);  \
    const float4 a2 = *reinterpret_cast<const float4*>((XP) + 8);  \
    const float4 a3 = *reinterpret_cast<const float4*>((XP) + 12); \
    acc[0]  = fmaf((WK), a0.x, acc[0]);  acc[1]  = fmaf((WK), a0.y, acc[1]);  \
    acc[2]  = fmaf((WK), a0.z, acc[2]);  acc[3]  = fmaf((WK), a0.w, acc[3]);  \
    acc[4]  = fmaf((WK), a1.x, acc[4]);  acc[5]  = fmaf((WK), a1.y, acc[5]);  \
    acc[6]  = fmaf((WK), a1.z, acc[6]);  acc[7]  = fmaf((WK), a1.w, acc[7]);  \
    acc[8]  = fmaf((WK), a2.x, acc[8]);  acc[9]  = fmaf((WK), a2.y, acc[9]);  \
    acc[10] = fmaf((WK), a2.z, acc[10]); acc[11] = fmaf((WK), a2.w, acc[11]); \
    acc[12] = fmaf((WK), a3.x, acc[12]); acc[13] = fmaf((WK), a3.y, acc[13]); \
    acc[14] = fmaf((WK), a3.z, acc[14]); acc[15] = fmaf((WK), a3.w, acc[15]); }

// ---------------------------------------------------------------------------
// Main fused kernel: one block (128 thr = output channel) per (b, p).
// Ball query on wave 0 -> idxs/gxs in LDS.
// X tiles live in per-block GLOBAL scratch laid out [c][j]: thread o writes
// its own contiguous row (c=o), and the compute loops read rows via
// wave-uniform addresses -> compiler scalarizes to s_load (SGPR broadcast).
// Inner loop is pure v_fma(sgpr_x, vgpr_w, acc): no ds_read, no addr math.
// ---------------------------------------------------------------------------
__global__ __launch_bounds__(128) void main_kernel(
    const float* __restrict__ xyz, const int* __restrict__ inds,
    const float* __restrict__ G, float* xsc_all,
    const float* __restrict__ w0x, const float* __restrict__ s0v, const float* __restrict__ t0v,
    const float* __restrict__ w1q, const float* __restrict__ s1v, const float* __restrict__ t1v,
    const float* __restrict__ w2q, const float* __restrict__ s2v, const float* __restrict__ t2v,
    const float* __restrict__ fq1, const float* __restrict__ fs1, const float* __restrict__ ft1,
    const float* __restrict__ fq2, const float* __restrict__ fs2, const float* __restrict__ ft2,
    const float* __restrict__ w3q, const float* __restrict__ b3, float* __restrict__ out)
{
  const int bid = blockIdx.x;           // == b*NP + p
  const int b = bid >> 8;
  const int p = bid & 255;
  const int o = threadIdx.x;
  __shared__ __align__(16) float fsh[NH];
  __shared__ __align__(16) float hsh[NH];
  __shared__ float gxs[NS][3];
  __shared__ int   idxs[NS];

  const float* xb = xyz + b * NPTS * 3;
  float* xs = xsc_all + (size_t)bid * (NH * NS);   // 8KB per block, [c][j]

  // ---- fused ball query on wave 0 (bit-identical to reference) ----
  if (o < 64) {
    const int lane = o;
    const int ci = inds[bid];
    const float cx = xb[ci * 3 + 0], cy = xb[ci * 3 + 1], cz = xb[ci * 3 + 2];
    float nq;
    {
#pragma clang fp contract(off)
      nq = (cx * cx + cy * cy) + cz * cz;
    }
    const float R2 = 0.09f;
    unsigned mask = 0;
    int cnt = 0, firstn = NPTS;
    for (int j = 0; j < 16; ++j) {
#pragma clang fp contract(off)
      int n = lane * 16 + j;     // lane-major: global order == lexicographic
      float x = xb[n * 3 + 0], y = xb[n * 3 + 1], z = xb[n * 3 + 2];
      float nx = (x * x + y * y) + z * z;
      float dt = (cx * x + cy * y) + cz * z;
      float d2 = (nq + nx) - 2.0f * dt;
      if (d2 < R2) { mask |= 1u << j; ++cnt; if (firstn == NPTS) firstn = n; }
    }
    int inc = cnt;
    for (int off = 1; off < 64; off <<= 1) {
      int v = __shfl_up(inc, off);
      if (lane >= off) inc += v;
    }
    int rank  = inc - cnt;
    int total = __shfl(inc, 63);
    for (int j = 0; j < 16; ++j) {
      if (mask & (1u << j)) {
        if (rank < NS) {
          int n = lane * 16 + j;
          idxs[rank] = n;
          float x = xb[n * 3 + 0], y = xb[n * 3 + 1], z = xb[n * 3 + 2];
          gxs[rank][0] = (x - cx) / 0.3f;
          gxs[rank][1] = (y - cy) / 0.3f;
          gxs[rank][2] = (z - cz) / 0.3f;
        }
        ++rank;
      }
    }
    int fmin = firstn;
    for (int off2 = 32; off2 > 0; off2 >>= 1) {
      int ov = __shfl_xor(fmin, off2);
      fmin = min(fmin, ov);
    }
    if (lane < NS && lane >= total) {
      idxs[lane] = fmin;
      float x = xb[fmin * 3 + 0], y = xb[fmin * 3 + 1], z = xb[fmin * 3 + 2];
      gxs[lane][0] = (x - cx) / 0.3f;
      gxs[lane][1] = (y - cy) / 0.3f;
      gxs[lane][2] = (z - cz) / 0.3f;
    }
  }
  __syncthreads();

  // ---- L0: thread o computes channel-row x1[c=o][j=0..15], stores 64B ----
  {
    const float wxa = w0x[o], wxb = w0x[NH + o], wxc = w0x[2 * NH + o];
    const float s0 = s0v[o], t0 = t0v[o];
    float xrow[16];
#pragma unroll
    for (int j = 0; j < NS; ++j) {
      int nj = idxs[j];
      float g = G[(b * NPTS + nj) * NH + o];
      float y = fmaf(wxa, gxs[j][0], fmaf(wxb, gxs[j][1], fmaf(wxc, gxs[j][2], g)));
      xrow[j] = fmaxf(fmaf(y, s0, t0), 0.0f);
    }
#pragma unroll
    for (int q = 0; q < 4; ++q)
      *reinterpret_cast<float4*>(xs + o * 16 + q * 4) =
          make_float4(xrow[4 * q], xrow[4 * q + 1], xrow[4 * q + 2], xrow[4 * q + 3]);
  }
  __syncthreads();   // drains vmcnt: x1 visible; then read via uniform s_load

  float acc[16];

  // ---- L1: acc[j] = sum_c w1[o][c] * x1[c][j] ----
#pragma unroll
  for (int j = 0; j < 16; ++j) acc[j] = 0.0f;
#pragma unroll 2
  for (int c4 = 0; c4 < 32; ++c4) {
    const float4 w = reinterpret_cast<const float4*>(w1q)[c4 * 128 + o];
    const float* xr = xs + c4 * 64;     // uniform address
    FMA16(w.x, xr + 0);
    FMA16(w.y, xr + 16);
    FMA16(w.z, xr + 32);
    FMA16(w.w, xr + 48);
  }
  __syncthreads();   // all waves done reading x1 before overwrite
  {
    const float s1 = s1v[o], t1 = t1v[o];
    float xrow[16];
#pragma unroll
    for (int j = 0; j < 16; ++j) xrow[j] = fmaxf(fmaf(acc[j], s1, t1), 0.0f);
#pragma unroll
    for (int q = 0; q < 4; ++q)
      *reinterpret_cast<float4*>(xs + o * 16 + q * 4) =
          make_float4(xrow[4 * q], xrow[4 * q + 1], xrow[4 * q + 2], xrow[4 * q + 3]);
  }
  __syncthreads();   // x2 visible

  // ---- L2 + maxpool ----
#pragma unroll
  for (int j = 0; j < 16; ++j) acc[j] = 0.0f;
#pragma unroll 2
  for (int c4 = 0; c4 < 32; ++c4) {
    const float4 w = reinterpret_cast<const float4*>(w2q)[c4 * 128 + o];
    const float* xr = xs + c4 * 64;
    FMA16(w.x, xr + 0);
    FMA16(w.y, xr + 16);
    FMA16(w.z, xr + 32);
    FMA16(w.w, xr + 48);
  }
  {
    const float s2 = s2v[o], t2 = t2v[o];
    float fo = 0.0f;
#pragma unroll
    for (int j = 0; j < 16; ++j) fo = fmaxf(fo, fmaxf(fmaf(acc[j], s2, t2), 0.0f));
    fsh[o] = fo;
  }
  __syncthreads();

  // ---- FC1 ----
  {
    float a = 0.0f;
#pragma unroll 4
    for (int c4 = 0; c4 < 32; ++c4) {
      const float4 w = reinterpret_cast<const float4*>(fq1)[c4 * 128 + o];
      const float4 fv = *reinterpret_cast<const float4*>(&fsh[c4 * 4]);
      a = fmaf(w.x, fv.x, fmaf(w.y, fv.y, fmaf(w.z, fv.z, fmaf(w.w, fv.w, a))));
    }
    hsh[o] = fmaxf(fmaf(a, fs1[o], ft1[o]), 0.0f);
  }
  __syncthreads();

  // ---- FC2 (overwrites fsh; FC1's fsh reads completed at barrier above) ----
  {
    float a = 0.0f;
#pragma unroll 4
    for (int c4 = 0; c4 < 32; ++c4) {
      const float4 w = reinterpret_cast<const float4*>(fq2)[c4 * 128 + o];
      const float4 hv = *reinterpret_cast<const float4*>(&hsh[c4 * 4]);
      a = fmaf(w.x, hv.x, fmaf(w.y, hv.y, fmaf(w.z, hv.z, fmaf(w.w, hv.w, a))));
    }
    fsh[o] = fmaxf(fmaf(a, fs2[o], ft2[o]), 0.0f);
  }
  __syncthreads();

  // ---- FC3 ----
  {
    float a = b3[o < NOUT ? o : 0];
#pragma unroll 4
    for (int c4 = 0; c4 < 32; ++c4) {
      const float4 w = reinterpret_cast<const float4*>(w3q)[c4 * 128 + o];
      const float4 hv = *reinterpret_cast<const float4*>(&fsh[c4 * 4]);
      a = fmaf(w.x, hv.x, fmaf(w.y, hv.y, fmaf(w.z, hv.z, fmaf(w.w, hv.w, a))));
    }
    if (o < NOUT) out[(b * NOUT + o) * NP + p] = a;
  }
}

extern "C" void kernel_launch(void* const* d_in, const int* in_sizes, int n_in,
                              void* d_out, int out_size, void* d_ws, size_t ws_size,
                              hipStream_t stream) {
  const float* xyz      = (const float*)d_in[0];
  const float* features = (const float*)d_in[1];
  const float* sa_w0 = (const float*)d_in[2];
  const float* sa_s0 = (const float*)d_in[3];
  const float* sa_t0 = (const float*)d_in[4];
  const float* sa_w1 = (const float*)d_in[5];
  const float* sa_s1 = (const float*)d_in[6];
  const float* sa_t1 = (const float*)d_in[7];
  const float* sa_w2 = (const float*)d_in[8];
  const float* sa_s2 = (const float*)d_in[9];
  const float* sa_t2 = (const float*)d_in[10];
  const float* fc_w1 = (const float*)d_in[11];
  const float* fc_s1 = (const float*)d_in[12];
  const float* fc_t1 = (const float*)d_in[13];
  const float* fc_w2 = (const float*)d_in[14];
  const float* fc_s2 = (const float*)d_in[15];
  const float* fc_t2 = (const float*)d_in[16];
  const float* fc_w3 = (const float*)d_in[17];
  const float* fc_b3 = (const float*)d_in[18];
  float* out = (float*)d_out;

  char* ws = (char*)d_ws;
  int* inds = (int*)ws;            ws += (size_t)NB * NP * sizeof(int);
  float* w0ft = (float*)ws;        ws += (size_t)256 * 128 * sizeof(float);
  float* w0x  = (float*)ws;        ws += (size_t)3 * 128 * sizeof(float);
  float* w1q  = (float*)ws;        ws += (size_t)128 * 128 * sizeof(float);
  float* w2q  = (float*)ws;        ws += (size_t)128 * 128 * sizeof(float);
  float* fq1  = (float*)ws;        ws += (size_t)128 * 128 * sizeof(float);
  float* fq2  = (float*)ws;        ws += (size_t)128 * 128 * sizeof(float);
  float* w3q  = (float*)ws;        ws += (size_t)128 * 128 * sizeof(float);
  float* G    = (float*)ws;        ws += (size_t)NB * NPTS * NH * sizeof(float);
  float* xsc  = (float*)ws;        ws += (size_t)NB * NP * NH * NS * sizeof(float);

  prep_kernel<<<128, 256, 0, stream>>>(sa_w0, sa_w1, sa_w2, fc_w1, fc_w2, fc_w3,
                                       w0ft, w0x, w1q, w2q, fq1, fq2, w3q);
  fused_fps_gfeat_kernel<<<NB + NB * (NPTS / GTN), 128, 0, stream>>>(
      xyz, inds, features, w0ft, G);
  main_kernel<<<NB * NP, 128, 0, stream>>>(
      xyz, inds, G, xsc,
      w0x, sa_s0, sa_t0,
      w1q, sa_s1, sa_t1,
      w2q, sa_s2, sa_t2,
      fq1, fc_s1, fc_t1,
      fq2, fc_s2, fc_t2,
      w3q, fc_b3, out);
}

// Round 5
// 469.414 us; speedup vs baseline: 1.5944x; 1.5944x over previous
//
#include <hip/hip_runtime.h>

#define NB 32
#define NPTS 1024
#define NP 256
#define NS 16
#define NC 256
#define NH 128
#define NOUT 97

// ---------------------------------------------------------------------------
// Prep. Lane-split weight layouts for the 4-o-per-lane / c-split-2 scheme:
//   wl[(c*32+og)*4+k] = W[og+32k][c]   (one dwordx4 per (c, o-group))
// w0l is the same for the 256-channel layer-0 feature GEMM.
// ---------------------------------------------------------------------------
__global__ __launch_bounds__(256) void prep_kernel(
    const float* __restrict__ sa_w0, const float* __restrict__ sa_w1,
    const float* __restrict__ sa_w2, const float* __restrict__ fc_w1,
    const float* __restrict__ fc_w2, const float* __restrict__ fc_w3,
    float* __restrict__ w0l, float* __restrict__ w0x,
    float* __restrict__ wl1, float* __restrict__ wl2,
    float* __restrict__ fl1, float* __restrict__ fl2,
    float* __restrict__ fl3)
{
  int t = blockIdx.x * 256 + threadIdx.x;
  if (t >= 256 * 128) return;
  int c = t >> 7, o = t & 127;
  int og = o & 31, k = o >> 5;
  w0l[(c * 32 + og) * 4 + k] = sa_w0[o * 259 + 3 + c];
  if (c < 3) w0x[c * 128 + o] = sa_w0[o * 259 + c];
  if (c < 128) {
    int qi = (c * 32 + og) * 4 + k;
    wl1[qi] = sa_w1[o * 128 + c];
    wl2[qi] = sa_w2[o * 128 + c];
    fl1[qi] = fc_w1[o * 128 + c];
    fl2[qi] = fc_w2[o * 128 + c];
    fl3[qi] = (o < NOUT) ? fc_w3[o * 128 + c] : 0.0f;
  }
}

// pair-add across lanes l <-> l^1 via DPP quad_perm [1,0,3,2] (VALU, no LDS)
__device__ __forceinline__ float dpp_pair_add(float v) {
  float ov = __int_as_float(
      __builtin_amdgcn_mov_dpp(__float_as_int(v), 0xB1, 0xF, 0xF, true));
  return v + ov;
}

// ---------------------------------------------------------------------------
// Fused FPS + gfeat, 64-thread (1-wave) blocks.
//   blocks [0, NB):       FPS, one wave per batch. u64 key (hi=dist bits,
//                         lo=1023-idx) -> max == first-max. Butterfly:
//                         xor1/2 DPP quad_perm, xor4/8/16 ds_swizzle,
//                         xor32 shfl.
//   blocks [NB, NB+2048): G[b][n][o] = sum_c features[b][c][n] * w0[o][3+c].
//                         Wave per 16-n tile; lane=(og,cg): 4 o's, 128-c half;
//                         DPP pair-add combines the two c-halves.
// ---------------------------------------------------------------------------
__global__ __launch_bounds__(64, 4) void fused_fps_gfeat_kernel(
    const float* __restrict__ xyz, int* __restrict__ inds,
    const float* __restrict__ features, const float* __restrict__ w0l,
    float* __restrict__ G)
{
  __shared__ __align__(16) float smem[NC * 16];   // 16 KB
  const int lane = threadIdx.x;

  if (blockIdx.x < NB) {
    // ------------------------- FPS -------------------------
    const int b = blockIdx.x;
    const float* xb = xyz + b * NPTS * 3;
    float pts[48];
    const float4* src = reinterpret_cast<const float4*>(xb + lane * 48);
#pragma unroll
    for (int r = 0; r < 12; ++r) {
      float4 v = src[r];
      pts[4 * r + 0] = v.x; pts[4 * r + 1] = v.y;
      pts[4 * r + 2] = v.z; pts[4 * r + 3] = v.w;
      *reinterpret_cast<float4*>(smem + lane * 48 + 4 * r) = v;   // raw mirror
    }
    float dist[16];
#pragma unroll
    for (int j = 0; j < 16; ++j) dist[j] = 1e10f;
    int far = 0;
    for (int i = 0; i < NP; ++i) {
      if (lane == 0) inds[b * NP + i] = far;
      float cx = smem[far * 3 + 0], cy = smem[far * 3 + 1], cz = smem[far * 3 + 2];
      unsigned long long bk = 0ull;
#pragma unroll
      for (int j = 0; j < 16; ++j) {
#pragma clang fp contract(off)
        float dx = pts[3 * j + 0] - cx;
        float dy = pts[3 * j + 1] - cy;
        float dz = pts[3 * j + 2] - cz;
        float d = (dx * dx + dy * dy) + dz * dz;
        float nd = fminf(dist[j], d);
        dist[j] = nd;
        unsigned long long key =
            ((unsigned long long)__float_as_uint(nd) << 32)
            | (unsigned)(1023 - (lane * 16 + j));
        bk = (key > bk) ? key : bk;
      }
      unsigned hi = (unsigned)(bk >> 32), lo = (unsigned)bk;
      // xor1, xor2: DPP quad_perm (VALU)
      {
        unsigned ohi = (unsigned)__builtin_amdgcn_mov_dpp((int)hi, 0xB1, 0xF, 0xF, true);
        unsigned olo = (unsigned)__builtin_amdgcn_mov_dpp((int)lo, 0xB1, 0xF, 0xF, true);
        if (ohi > hi || (ohi == hi && olo > lo)) { hi = ohi; lo = olo; }
      }
      {
        unsigned ohi = (unsigned)__builtin_amdgcn_mov_dpp((int)hi, 0x4E, 0xF, 0xF, true);
        unsigned olo = (unsigned)__builtin_amdgcn_mov_dpp((int)lo, 0x4E, 0xF, 0xF, true);
        if (ohi > hi || (ohi == hi && olo > lo)) { hi = ohi; lo = olo; }
      }
      // xor4/8/16: ds_swizzle (within 32-lane groups)
      {
        unsigned ohi = (unsigned)__builtin_amdgcn_ds_swizzle((int)hi, 0x101F);
        unsigned olo = (unsigned)__builtin_amdgcn_ds_swizzle((int)lo, 0x101F);
        if (ohi > hi || (ohi == hi && olo > lo)) { hi = ohi; lo = olo; }
      }
      {
        unsigned ohi = (unsigned)__builtin_amdgcn_ds_swizzle((int)hi, 0x201F);
        unsigned olo = (unsigned)__builtin_amdgcn_ds_swizzle((int)lo, 0x201F);
        if (ohi > hi || (ohi == hi && olo > lo)) { hi = ohi; lo = olo; }
      }
      {
        unsigned ohi = (unsigned)__builtin_amdgcn_ds_swizzle((int)hi, 0x401F);
        unsigned olo = (unsigned)__builtin_amdgcn_ds_swizzle((int)lo, 0x401F);
        if (ohi > hi || (ohi == hi && olo > lo)) { hi = ohi; lo = olo; }
      }
      // xor32: cross-half
      {
        unsigned ohi = (unsigned)__shfl_xor((int)hi, 32);
        unsigned olo = (unsigned)__shfl_xor((int)lo, 32);
        if (ohi > hi || (ohi == hi && olo > lo)) { hi = ohi; lo = olo; }
      }
      far = 1023 - (int)lo;
    }
    return;
  }

  // ------------------------- gfeat -------------------------
  const int blk = blockIdx.x - NB;
  const int b  = blk >> 6;
  const int n0 = (blk & 63) * 16;
  const int og = lane >> 1;
  const int cg = lane & 1;
  const float* fb = features + b * NC * NPTS;
  // stage f[c][n0..n0+15]: lane stages rows c = lane, lane+64, lane+128, lane+192
#pragma unroll
  for (int r = 0; r < 4; ++r) {
    int c = r * 64 + lane;
    const float4* s4 = reinterpret_cast<const float4*>(fb + c * NPTS + n0);
    float4 v0 = s4[0], v1 = s4[1], v2 = s4[2], v3 = s4[3];
    float* row = smem + c * 16;
    reinterpret_cast<float4*>(row)[0] = v0;
    reinterpret_cast<float4*>(row)[1] = v1;
    reinterpret_cast<float4*>(row)[2] = v2;
    reinterpret_cast<float4*>(row)[3] = v3;
  }
  // single wave: LDS ops execute in program order; compiler inserts lgkmcnt.
  float acc[4][16];
#pragma unroll
  for (int k = 0; k < 4; ++k)
#pragma unroll
    for (int j = 0; j < 16; ++j) acc[k][j] = 0.0f;
  const int cb = cg * 128;
#pragma unroll 2
  for (int cl = 0; cl < 128; ++cl) {
    int c = cb + cl;
    const float4 wq = *reinterpret_cast<const float4*>(w0l + (c * 32 + og) * 4);
    const float* row = smem + c * 16;
    const float4 x0 = reinterpret_cast<const float4*>(row)[0];
    const float4 x1 = reinterpret_cast<const float4*>(row)[1];
    const float4 x2 = reinterpret_cast<const float4*>(row)[2];
    const float4 x3 = reinterpret_cast<const float4*>(row)[3];
    const float wk[4] = {wq.x, wq.y, wq.z, wq.w};
    const float xr[16] = {x0.x, x0.y, x0.z, x0.w, x1.x, x1.y, x1.z, x1.w,
                          x2.x, x2.y, x2.z, x2.w, x3.x, x3.y, x3.z, x3.w};
#pragma unroll
    for (int k = 0; k < 4; ++k)
#pragma unroll
      for (int j = 0; j < 16; ++j)
        acc[k][j] = fmaf(wk[k], xr[j], acc[k][j]);
  }
#pragma unroll
  for (int k = 0; k < 4; ++k)
#pragma unroll
    for (int j = 0; j < 16; ++j) acc[k][j] = dpp_pair_add(acc[k][j]);
  // store: lane stores k = 2cg, 2cg+1  -> full o coverage, no duplicates
#pragma unroll
  for (int m = 0; m < 2; ++m) {
    int k = cg * 2 + m;
    int o = og + 32 * k;
#pragma unroll
    for (int j = 0; j < 16; ++j)
      G[(b * NPTS + n0 + j) * NH + o] = acc[k][j];
  }
}

// ---------------------------------------------------------------------------
// Main kernel: 128-thread blocks = 2 independent waves, each wave owns one
// (b,p) tile. No __syncthreads anywhere (wave-lockstep ordering).
// Per wave: ball query -> L0 (G gather + coords) -> L1 -> L2+maxpool ->
// FC1 -> FC2 -> FC3. lane=(og=lane>>1, cg=lane&1): 4 o's per lane, 64-c half;
// DPP pair-add merges c-halves. X tile in LDS [c][j], rows 64B.
// ---------------------------------------------------------------------------
__global__ __launch_bounds__(128, 4) void main_kernel(
    const float* __restrict__ xyz, const int* __restrict__ inds,
    const float* __restrict__ G,
    const float* __restrict__ w0x, const float* __restrict__ s0v, const float* __restrict__ t0v,
    const float* __restrict__ wl1, const float* __restrict__ s1v, const float* __restrict__ t1v,
    const float* __restrict__ wl2, const float* __restrict__ s2v, const float* __restrict__ t2v,
    const float* __restrict__ fl1, const float* __restrict__ fs1, const float* __restrict__ ft1,
    const float* __restrict__ fl2, const float* __restrict__ fs2, const float* __restrict__ ft2,
    const float* __restrict__ fl3, const float* __restrict__ b3, float* __restrict__ out)
{
  __shared__ __align__(16) float xt[2][NH][NS];   // 16 KB (2 waves)
  __shared__ float gxs[2][NS][3];
  __shared__ int   idxs[2][NS];

  const int w    = threadIdx.x >> 6;
  const int lane = threadIdx.x & 63;
  const int bid  = blockIdx.x * 2 + w;            // == b*NP + p
  const int b = bid >> 8;
  const int p = bid & 255;
  const int og = lane >> 1;
  const int cg = lane & 1;
  const int cb = cg * 64;

  const float* xb = xyz + b * NPTS * 3;
  float* xs = &xt[w][0][0];

  // ---- ball query (bit-identical to reference), one wave ----
  {
    const int ci = inds[bid];
    const float cx = xb[ci * 3 + 0], cy = xb[ci * 3 + 1], cz = xb[ci * 3 + 2];
    float nq;
    {
#pragma clang fp contract(off)
      nq = (cx * cx + cy * cy) + cz * cz;
    }
    const float R2 = 0.09f;
    unsigned mask = 0;
    int cnt = 0, firstn = NPTS;
    for (int j = 0; j < 16; ++j) {
#pragma clang fp contract(off)
      int n = lane * 16 + j;   // lane-major: global order == lexicographic
      float x = xb[n * 3 + 0], y = xb[n * 3 + 1], z = xb[n * 3 + 2];
      float nx = (x * x + y * y) + z * z;
      float dt = (cx * x + cy * y) + cz * z;
      float d2 = (nq + nx) - 2.0f * dt;
      if (d2 < R2) { mask |= 1u << j; ++cnt; if (firstn == NPTS) firstn = n; }
    }
    int inc = cnt;
    for (int off = 1; off < 64; off <<= 1) {
      int v = __shfl_up(inc, off);
      if (lane >= off) inc += v;
    }
    int rank  = inc - cnt;
    int total = __shfl(inc, 63);
    for (int j = 0; j < 16; ++j) {
      if (mask & (1u << j)) {
        if (rank < NS) {
          int n = lane * 16 + j;
          idxs[w][rank] = n;
          float x = xb[n * 3 + 0], y = xb[n * 3 + 1], z = xb[n * 3 + 2];
          gxs[w][rank][0] = (x - cx) / 0.3f;
          gxs[w][rank][1] = (y - cy) / 0.3f;
          gxs[w][rank][2] = (z - cz) / 0.3f;
        }
        ++rank;
      }
    }
    int fmin = firstn;
    for (int off2 = 32; off2 > 0; off2 >>= 1) {
      int ov = __shfl_xor(fmin, off2);
      fmin = min(fmin, ov);
    }
    if (lane < NS && lane >= total) {
      idxs[w][lane] = fmin;
      float x = xb[fmin * 3 + 0], y = xb[fmin * 3 + 1], z = xb[fmin * 3 + 2];
      gxs[w][lane][0] = (x - cx) / 0.3f;
      gxs[w][lane][1] = (y - cy) / 0.3f;
      gxs[w][lane][2] = (z - cz) / 0.3f;
    }
  }

  // ---- L0: lane computes x1 rows (lane) and (lane+64) ----
  {
    const float wa0 = w0x[lane],      wb0 = w0x[128 + lane],      wc0 = w0x[256 + lane];
    const float wa1 = w0x[lane + 64], wb1 = w0x[128 + lane + 64], wc1 = w0x[256 + lane + 64];
    const float ss0 = s0v[lane], tt0 = t0v[lane];
    const float ss1 = s0v[lane + 64], tt1 = t0v[lane + 64];
    float r0[16], r1[16];
#pragma unroll
    for (int j = 0; j < 16; ++j) {
      int nj = idxs[w][j];
      float gx = gxs[w][j][0], gy = gxs[w][j][1], gz = gxs[w][j][2];
      const float* gp = G + (b * NPTS + nj) * NH;
      float g0 = gp[lane], g1 = gp[lane + 64];
      float y0 = fmaf(wa0, gx, fmaf(wb0, gy, fmaf(wc0, gz, g0)));
      float y1 = fmaf(wa1, gx, fmaf(wb1, gy, fmaf(wc1, gz, g1)));
      r0[j] = fmaxf(fmaf(y0, ss0, tt0), 0.0f);
      r1[j] = fmaxf(fmaf(y1, ss1, tt1), 0.0f);
    }
    float* rowA = xs + lane * 16;
    float* rowB = xs + (lane + 64) * 16;
#pragma unroll
    for (int q = 0; q < 4; ++q) {
      reinterpret_cast<float4*>(rowA)[q] =
          make_float4(r0[4 * q], r0[4 * q + 1], r0[4 * q + 2], r0[4 * q + 3]);
      reinterpret_cast<float4*>(rowB)[q] =
          make_float4(r1[4 * q], r1[4 * q + 1], r1[4 * q + 2], r1[4 * q + 3]);
    }
  }

  float acc[4][16];

  // ---- L1 ----
#pragma unroll
  for (int k = 0; k < 4; ++k)
#pragma unroll
    for (int j = 0; j < 16; ++j) acc[k][j] = 0.0f;
#pragma unroll 2
  for (int cl = 0; cl < 64; ++cl) {
    int c = cb + cl;
    const float4 wq = *reinterpret_cast<const float4*>(wl1 + (c * 32 + og) * 4);
    const float* row = xs + c * 16;
    const float4 x0 = reinterpret_cast<const float4*>(row)[0];
    const float4 x1 = reinterpret_cast<const float4*>(row)[1];
    const float4 x2 = reinterpret_cast<const float4*>(row)[2];
    const float4 x3 = reinterpret_cast<const float4*>(row)[3];
    const float wk[4] = {wq.x, wq.y, wq.z, wq.w};
    const float xr[16] = {x0.x, x0.y, x0.z, x0.w, x1.x, x1.y, x1.z, x1.w,
                          x2.x, x2.y, x2.z, x2.w, x3.x, x3.y, x3.z, x3.w};
#pragma unroll
    for (int k = 0; k < 4; ++k)
#pragma unroll
      for (int j = 0; j < 16; ++j)
        acc[k][j] = fmaf(wk[k], xr[j], acc[k][j]);
  }
#pragma unroll
  for (int k = 0; k < 4; ++k)
#pragma unroll
    for (int j = 0; j < 16; ++j) acc[k][j] = dpp_pair_add(acc[k][j]);
  // BN+ReLU, write x2 rows (lane writes k = 2cg, 2cg+1) — after all reads
#pragma unroll
  for (int m = 0; m < 2; ++m) {
    int k = cg * 2 + m;
    int o = og + 32 * k;
    const float ss = s1v[o], tt = t1v[o];
    float r[16];
#pragma unroll
    for (int j = 0; j < 16; ++j) r[j] = fmaxf(fmaf(acc[k][j], ss, tt), 0.0f);
    float* row = xs + o * 16;
#pragma unroll
    for (int q = 0; q < 4; ++q)
      reinterpret_cast<float4*>(row)[q] =
          make_float4(r[4 * q], r[4 * q + 1], r[4 * q + 2], r[4 * q + 3]);
  }

  // ---- L2 + maxpool ----
#pragma unroll
  for (int k = 0; k < 4; ++k)
#pragma unroll
    for (int j = 0; j < 16; ++j) acc[k][j] = 0.0f;
#pragma unroll 2
  for (int cl = 0; cl < 64; ++cl) {
    int c = cb + cl;
    const float4 wq = *reinterpret_cast<const float4*>(wl2 + (c * 32 + og) * 4);
    const float* row = xs + c * 16;
    const float4 x0 = reinterpret_cast<const float4*>(row)[0];
    const float4 x1 = reinterpret_cast<const float4*>(row)[1];
    const float4 x2 = reinterpret_cast<const float4*>(row)[2];
    const float4 x3 = reinterpret_cast<const float4*>(row)[3];
    const float wk[4] = {wq.x, wq.y, wq.z, wq.w};
    const float xr[16] = {x0.x, x0.y, x0.z, x0.w, x1.x, x1.y, x1.z, x1.w,
                          x2.x, x2.y, x2.z, x2.w, x3.x, x3.y, x3.z, x3.w};
#pragma unroll
    for (int k = 0; k < 4; ++k)
#pragma unroll
      for (int j = 0; j < 16; ++j)
        acc[k][j] = fmaf(wk[k], xr[j], acc[k][j]);
  }
#pragma unroll
  for (int k = 0; k < 4; ++k)
#pragma unroll
    for (int j = 0; j < 16; ++j) acc[k][j] = dpp_pair_add(acc[k][j]);
  // BN+ReLU+max over j; write f vector into xs[0..127] (x2 fully consumed)
#pragma unroll
  for (int m = 0; m < 2; ++m) {
    int k = cg * 2 + m;
    int o = og + 32 * k;
    const float ss = s2v[o], tt = t2v[o];
    float fo = 0.0f;
#pragma unroll
    for (int j = 0; j < 16; ++j)
      fo = fmaxf(fo, fmaxf(fmaf(acc[k][j], ss, tt), 0.0f));
    xs[o] = fo;
  }

  // ---- FC1: h (xs[128..255]) = relu(bn(fw1 @ f)) ----
  {
    float h4[4] = {0.0f, 0.0f, 0.0f, 0.0f};
#pragma unroll 4
    for (int cl = 0; cl < 64; ++cl) {
      int c = cb + cl;
      const float fvv = xs[c];
      const float4 wq = *reinterpret_cast<const float4*>(fl1 + (c * 32 + og) * 4);
      h4[0] = fmaf(wq.x, fvv, h4[0]);
      h4[1] = fmaf(wq.y, fvv, h4[1]);
      h4[2] = fmaf(wq.z, fvv, h4[2]);
      h4[3] = fmaf(wq.w, fvv, h4[3]);
    }
#pragma unroll
    for (int k = 0; k < 4; ++k) h4[k] = dpp_pair_add(h4[k]);
#pragma unroll
    for (int m = 0; m < 2; ++m) {
      int k = cg * 2 + m;
      int o = og + 32 * k;
      xs[128 + o] = fmaxf(fmaf(h4[k], fs1[o], ft1[o]), 0.0f);
    }
  }

  // ---- FC2: f2 (xs[0..127]) = relu(bn(fw2 @ h)) ----
  {
    float h4[4] = {0.0f, 0.0f, 0.0f, 0.0f};
#pragma unroll 4
    for (int cl = 0; cl < 64; ++cl) {
      int c = cb + cl;
      const float fvv = xs[128 + c];
      const float4 wq = *reinterpret_cast<const float4*>(fl2 + (c * 32 + og) * 4);
      h4[0] = fmaf(wq.x, fvv, h4[0]);
      h4[1] = fmaf(wq.y, fvv, h4[1]);
      h4[2] = fmaf(wq.z, fvv, h4[2]);
      h4[3] = fmaf(wq.w, fvv, h4[3]);
    }
#pragma unroll
    for (int k = 0; k < 4; ++k) h4[k] = dpp_pair_add(h4[k]);
#pragma unroll
    for (int m = 0; m < 2; ++m) {
      int k = cg * 2 + m;
      int o = og + 32 * k;
      xs[o] = fmaxf(fmaf(h4[k], fs2[o], ft2[o]), 0.0f);
    }
  }

  // ---- FC3 ----
  {
    float h4[4] = {0.0f, 0.0f, 0.0f, 0.0f};
#pragma unroll 4
    for (int cl = 0; cl < 64; ++cl) {
      int c = cb + cl;
      const float fvv = xs[c];
      const float4 wq = *reinterpret_cast<const float4*>(fl3 + (c * 32 + og) * 4);
      h4[0] = fmaf(wq.x, fvv, h4[0]);
      h4[1] = fmaf(wq.y, fvv, h4[1]);
      h4[2] = fmaf(wq.z, fvv, h4[2]);
      h4[3] = fmaf(wq.w, fvv, h4[3]);
    }
#pragma unroll
    for (int k = 0; k < 4; ++k) h4[k] = dpp_pair_add(h4[k]);
#pragma unroll
    for (int m = 0; m < 2; ++m) {
      int k = cg * 2 + m;
      int o = og + 32 * k;
      if (o < NOUT) out[(b * NOUT + o) * NP + p] = h4[k] + b3[o];
    }
  }
}

extern "C" void kernel_launch(void* const* d_in, const int* in_sizes, int n_in,
                              void* d_out, int out_size, void* d_ws, size_t ws_size,
                              hipStream_t stream) {
  const float* xyz      = (const float*)d_in[0];
  const float* features = (const float*)d_in[1];
  const float* sa_w0 = (const float*)d_in[2];
  const float* sa_s0 = (const float*)d_in[3];
  const float* sa_t0 = (const float*)d_in[4];
  const float* sa_w1 = (const float*)d_in[5];
  const float* sa_s1 = (const float*)d_in[6];
  const float* sa_t1 = (const float*)d_in[7];
  const float* sa_w2 = (const float*)d_in[8];
  const float* sa_s2 = (const float*)d_in[9];
  const float* sa_t2 = (const float*)d_in[10];
  const float* fc_w1 = (const float*)d_in[11];
  const float* fc_s1 = (const float*)d_in[12];
  const float* fc_t1 = (const float*)d_in[13];
  const float* fc_w2 = (const float*)d_in[14];
  const float* fc_s2 = (const float*)d_in[15];
  const float* fc_t2 = (const float*)d_in[16];
  const float* fc_w3 = (const float*)d_in[17];
  const float* fc_b3 = (const float*)d_in[18];
  float* out = (float*)d_out;

  char* ws = (char*)d_ws;
  int* inds = (int*)ws;            ws += (size_t)NB * NP * sizeof(int);
  float* w0l  = (float*)ws;        ws += (size_t)256 * 128 * sizeof(float);
  float* w0x  = (float*)ws;        ws += (size_t)3 * 128 * sizeof(float);
  float* wl1  = (float*)ws;        ws += (size_t)128 * 128 * sizeof(float);
  float* wl2  = (float*)ws;        ws += (size_t)128 * 128 * sizeof(float);
  float* fl1  = (float*)ws;        ws += (size_t)128 * 128 * sizeof(float);
  float* fl2  = (float*)ws;        ws += (size_t)128 * 128 * sizeof(float);
  float* fl3  = (float*)ws;        ws += (size_t)128 * 128 * sizeof(float);
  float* G    = (float*)ws;        ws += (size_t)NB * NPTS * NH * sizeof(float);

  prep_kernel<<<128, 256, 0, stream>>>(sa_w0, sa_w1, sa_w2, fc_w1, fc_w2, fc_w3,
                                       w0l, w0x, wl1, wl2, fl1, fl2, fl3);
  fused_fps_gfeat_kernel<<<NB + NB * (NPTS / 16), 64, 0, stream>>>(
      xyz, inds, features, w0l, G);
  main_kernel<<<NB * NP / 2, 128, 0, stream>>>(
      xyz, inds, G,
      w0x, sa_s0, sa_t0,
      wl1, sa_s1, sa_t1,
      wl2, sa_s2, sa_t2,
      fl1, fc_s1, fc_t1,
      fl2, fc_s2, fc_t2,
      fl3, fc_b3, out);
}